// Round 1
// baseline (52933.167 us; speedup 1.0000x reference)
//
#include <hip/hip_runtime.h>
#include <hip/hip_bf16.h>

#define DEV __device__ __forceinline__

DEV float fast_rcp(float x) {
#if __has_builtin(__builtin_amdgcn_rcpf)
  return __builtin_amdgcn_rcpf(x);
#else
  return 1.0f / x;
#endif
}
DEV float sigm(float x) { return fast_rcp(1.0f + __expf(-x)); }
DEV float tanh_f(float x) {
  float e = __expf(-2.0f * fabsf(x));
  float t = 1.0f - 2.0f * e * fast_rcp(1.0f + e);
  return copysignf(t, x);
}
DEV float lrelu(float x) { return x > 0.0f ? x : 0.01f * x; }

DEV float wave_sum(float v) {
#pragma unroll
  for (int m = 32; m; m >>= 1) v += __shfl_xor(v, m);
  return v;
}
DEV float wave_max(float v) {
#pragma unroll
  for (int m = 32; m; m >>= 1) v = fmaxf(v, __shfl_xor(v, m));
  return v;
}
DEV float dot4(float4 w, float4 x, float acc) {
  acc = fmaf(w.x, x.x, acc);
  acc = fmaf(w.y, x.y, acc);
  acc = fmaf(w.z, x.z, acc);
  acc = fmaf(w.w, x.w, acc);
  return acc;
}

// ---------------------------------------------------------------------------
// Fused 2-layer GRU. Block = 384 threads: waves 0-2 = layer0, waves 3-5 =
// layer1 (pipelined one timestep behind; h0_t handed off via LDS double
// buffer). 2 sequences per block. Per-thread: one gate-row (g,j), weights in
// registers, h-state read as float4 wave-broadcast from LDS.
// PyTorch gate order r,z,n: r=sig(xr+hr) z=sig(xz+hz) n=tanh(xn+r*hn),
// h=(1-z)n+z*h  (biases: x-side bih folded into ax, h-side bhh into ah).
// ---------------------------------------------------------------------------
template <int I0, bool WRITE_FULL>
__launch_bounds__(384, 3)
__global__ void gru2_fused(const float* __restrict__ xin, int sstride, int tstride, int T,
                           const float* __restrict__ Wih0, const float* __restrict__ Whh0,
                           const float* __restrict__ bih0, const float* __restrict__ bhh0,
                           const float* __restrict__ Wih1, const float* __restrict__ Whh1,
                           const float* __restrict__ bih1, const float* __restrict__ bhh1,
                           float* __restrict__ out_last, float* __restrict__ out_full) {
  constexpr int IPAD = (I0 > 8) ? 64 : 8;
  const int tid = threadIdx.x;
  const int group = tid / 192;      // 0 = layer0, 1 = layer1 (wave-uniform)
  const int lt = tid - group * 192;
  const int g = lt >> 6;            // gate: 0=r 1=z 2=n
  const int j = lt & 63;            // hidden unit
  const int row = g * 64 + j;       // gate row in [0,192)
  const int s0 = blockIdx.x * 2;    // first sequence of this block

  __shared__ __align__(16) float h0s[2][64];        // layer0 state per seq
  __shared__ __align__(16) float h1s[2][64];        // layer1 state
  __shared__ __align__(16) float h0out[2][2][64];   // [buf][seq][j] L0->L1 handoff
  __shared__ __align__(16) float xbuf[2][2][IPAD];  // staged input, double buffer
  __shared__ float gbuf[2][2][2][64];               // [group][gate r/z][seq][j]

  const float* bih = group ? bih1 : bih0;
  const float* bhh = group ? bhh1 : bhh0;
  const float bx = bih[row];
  const float bh = bhh[row];

  // recurrent weights (row of Whh) in registers
  float4 whh4[16];
  {
    const float* Whh = group ? Whh1 : Whh0;
    const float4* wp = (const float4*)(Whh + row * 64);
#pragma unroll
    for (int kk = 0; kk < 16; ++kk) whh4[kk] = wp[kk];
  }
  // input weights
  float4 wih4[16];
  float wih_s[(I0 <= 8) ? I0 : 1];
  if (group == 1) {
    const float4* wp = (const float4*)(Wih1 + row * 64);
#pragma unroll
    for (int kk = 0; kk < 16; ++kk) wih4[kk] = wp[kk];
  } else {
    if constexpr (I0 > 8) {
      const float4* wp = (const float4*)(Wih0 + row * 64);
#pragma unroll
      for (int kk = 0; kk < 16; ++kk) wih4[kk] = wp[kk];
    } else {
#pragma unroll
      for (int i = 0; i < I0; ++i) wih_s[i] = Wih0[row * I0 + i];
    }
  }

  // init states + stage x[t=0]
  if (tid < 128) { (&h0s[0][0])[tid] = 0.0f; (&h1s[0][0])[tid] = 0.0f; }
  if (tid < 2 * I0) {
    int s = tid / I0, i = tid - s * I0;
    xbuf[0][s][i] = xin[(size_t)(s0 + s) * sstride + i];
  }
  __syncthreads();

  for (int t = 0; t <= T; ++t) {
    const bool active = group ? (t >= 1) : (t < T);
    float ax0, ax1, ah0, ah1;

    // prefetch next x into registers (written to LDS in phase B)
    float xpre = 0.0f;
    int ps = 0, pi = 0;
    const bool do_pre = (tid < 2 * I0) && (t + 1 < T);
    if (do_pre) {
      ps = tid / I0; pi = tid - ps * I0;
      xpre = xin[(size_t)(s0 + ps) * sstride + (size_t)(t + 1) * tstride + pi];
    }

    if (active) {
      ax0 = bx; ax1 = bx; ah0 = bh; ah1 = bh;
      const float4* hr0 = (const float4*)(group ? h1s[0] : h0s[0]);
      const float4* hr1 = (const float4*)(group ? h1s[1] : h0s[1]);
#pragma unroll
      for (int kk = 0; kk < 16; ++kk) {
        float4 w = whh4[kk];
        ah0 = dot4(w, hr0[kk], ah0);
        ah1 = dot4(w, hr1[kk], ah1);
      }
      if (group == 1) {
        const float4* xr0 = (const float4*)(h0out[(t - 1) & 1][0]);
        const float4* xr1 = (const float4*)(h0out[(t - 1) & 1][1]);
#pragma unroll
        for (int kk = 0; kk < 16; ++kk) {
          float4 w = wih4[kk];
          ax0 = dot4(w, xr0[kk], ax0);
          ax1 = dot4(w, xr1[kk], ax1);
        }
      } else if constexpr (I0 > 8) {
        const float4* xr0 = (const float4*)(xbuf[t & 1][0]);
        const float4* xr1 = (const float4*)(xbuf[t & 1][1]);
#pragma unroll
        for (int kk = 0; kk < 16; ++kk) {
          float4 w = wih4[kk];
          ax0 = dot4(w, xr0[kk], ax0);
          ax1 = dot4(w, xr1[kk], ax1);
        }
      } else {
#pragma unroll
        for (int i = 0; i < I0; ++i) {
          float w = wih_s[i];
          ax0 = fmaf(w, xbuf[t & 1][0][i], ax0);
          ax1 = fmaf(w, xbuf[t & 1][1][i], ax1);
        }
      }
      if (g < 2) {
        gbuf[group][g][0][j] = sigm(ax0 + ah0);
        gbuf[group][g][1][j] = sigm(ax1 + ah1);
      }
    }
    __syncthreads();  // gates visible; L0's h0out[t-1] reads done before overwrite

    if (active && g == 2) {
#pragma unroll
      for (int s = 0; s < 2; ++s) {
        float axs = s ? ax1 : ax0;
        float ahs = s ? ah1 : ah0;
        float r = gbuf[group][0][s][j];
        float z = gbuf[group][1][s][j];
        float n = tanh_f(axs + r * ahs);
        float* hp = group ? h1s[s] : h0s[s];
        float hn = (1.0f - z) * n + z * hp[j];
        hp[j] = hn;
        if (group == 0) {
          h0out[t & 1][s][j] = hn;
        } else {
          const int step = t - 1;
          const int seq = s0 + s;
          if constexpr (WRITE_FULL) {
            out_full[((size_t)seq * T + step) * 64 + j] = hn;
          } else {
            if (step == T - 1) out_last[(size_t)seq * 64 + j] = hn;
          }
        }
      }
    }
    if (do_pre) xbuf[(t + 1) & 1][ps][pi] = xpre;
    __syncthreads();
  }
}

// ---------------------------------------------------------------------------
// GAT algebraic prep: v_dst[d] = sum_e trans_W[e][d]*a[e], v_src with a[64+e];
// c_dst/c_src from trans_b.  vbuf = [v_dst(64) | v_src(64) | c_dst | c_src]
// ---------------------------------------------------------------------------
__global__ void gat_prep(const float* __restrict__ tW, const float* __restrict__ tb,
                         const float* __restrict__ a, float* __restrict__ vbuf) {
  const int d = threadIdx.x;  // 64 threads
  float vd = 0.0f, vs = 0.0f;
  for (int e = 0; e < 64; ++e) {
    float w = tW[e * 64 + d];
    vd = fmaf(w, a[e], vd);
    vs = fmaf(w, a[64 + e], vs);
  }
  vbuf[d] = vd;
  vbuf[64 + d] = vs;
  if (d == 0) {
    float cd = 0.0f, cs = 0.0f;
    for (int e = 0; e < 64; ++e) {
      cd = fmaf(tb[e], a[e], cd);
      cs = fmaf(tb[e], a[64 + e], cs);
    }
    vbuf[128] = cd;
    vbuf[129] = cs;
  }
}

// s_src[n], s_dst[n] per encoder row (one wave per row)
__global__ void gat_svals(const float* __restrict__ h_enc, const float* __restrict__ vbuf,
                          float* __restrict__ s_src, float* __restrict__ s_dst) {
  const int wave = (blockIdx.x * blockDim.x + threadIdx.x) >> 6;
  const int lane = threadIdx.x & 63;
  float h = h_enc[(size_t)wave * 64 + lane];
  float pd = h * vbuf[lane];
  float ps = h * vbuf[64 + lane];
  pd = wave_sum(pd);
  ps = wave_sum(ps);
  if (lane == 0) {
    s_dst[wave] = pd + vbuf[128];
    s_src[wave] = ps + vbuf[129];
  }
}

// ---------------------------------------------------------------------------
// Dense all-pairs attention per group k (m=512): softmax_j leaky(s_i+s_j),
// weighted sum of h[k,j,:], + residual. One wave per row i; p-buffer in LDS
// (wave-private, no block barriers in the row loop); h streamed from L2.
// grid = 20 groups * 128 tiles, block = 256 (4 rows).
// ---------------------------------------------------------------------------
__launch_bounds__(256)
__global__ void gat_attn(const float* __restrict__ h_enc,
                         const float* __restrict__ s_src,
                         const float* __restrict__ s_dst,
                         float* __restrict__ hout) {
  const int k = blockIdx.x >> 7;
  const int tile = blockIdx.x & 127;
  const int wv = threadIdx.x >> 6;
  const int lane = threadIdx.x & 63;
  const int i = tile * 4 + wv;
  __shared__ float sdbuf[512];
  __shared__ __align__(16) float pbuf[4][512];

  for (int u = threadIdx.x; u < 512; u += 256) sdbuf[u] = s_dst[k * 512 + u];
  __syncthreads();

  const float si = s_src[k * 512 + i];
  float ev[8];
  float mx = -1e30f;
#pragma unroll
  for (int u = 0; u < 8; ++u) {
    ev[u] = lrelu(si + sdbuf[lane + u * 64]);
    mx = fmaxf(mx, ev[u]);
  }
  mx = wave_max(mx);
  float lsum = 0.0f;
#pragma unroll
  for (int u = 0; u < 8; ++u) {
    float p = __expf(ev[u] - mx);
    pbuf[wv][lane + u * 64] = p;
    lsum += p;
  }
  lsum = wave_sum(lsum);
  const float inv = fast_rcp(lsum);

  const float* hk = h_enc + (size_t)k * 512 * 64;
  const float4* pv = (const float4*)pbuf[wv];
  float acc0 = 0.0f, acc1 = 0.0f;
#pragma unroll 2
  for (int jj = 0; jj < 128; ++jj) {
    float4 p = pv[jj];
    const float* hp = hk + (size_t)(jj * 4) * 64 + lane;
    acc0 = fmaf(p.x, hp[0], acc0);
    acc1 = fmaf(p.y, hp[64], acc1);
    acc0 = fmaf(p.z, hp[128], acc0);
    acc1 = fmaf(p.w, hp[192], acc1);
  }
  hout[((size_t)k * 512 + i) * 64 + lane] =
      (acc0 + acc1) * inv + hk[(size_t)i * 64 + lane];
}

// ---------------------------------------------------------------------------
// Post-GAT transform: h2 = fc(hout); pred head (k==19); z = tanh(al_in(h2))
// written in [i][k][64] layout for the ALSTM scan. One wave per row.
// ---------------------------------------------------------------------------
__launch_bounds__(256)
__global__ void gat_out(const float* __restrict__ hin,
                        const float* __restrict__ fcW, const float* __restrict__ fcb,
                        const float* __restrict__ fcoW, const float* __restrict__ fcob,
                        const float* __restrict__ alinW, const float* __restrict__ alinb,
                        float* __restrict__ zout, float* __restrict__ pred) {
  const int wv = threadIdx.x >> 6;
  const int lane = threadIdx.x & 63;
  const int n = blockIdx.x * 4 + wv;  // [0,10240)
  const int k = n >> 9;
  const int i = n & 511;
  __shared__ __align__(16) float rbuf[4][64];
  __shared__ __align__(16) float rbuf2[4][64];

  float4 fw[16], aw[16];
  {
    const float4* p1 = (const float4*)(fcW + lane * 64);
    const float4* p2 = (const float4*)(alinW + lane * 64);
#pragma unroll
    for (int kk = 0; kk < 16; ++kk) fw[kk] = p1[kk];
#pragma unroll
    for (int kk = 0; kk < 16; ++kk) aw[kk] = p2[kk];
  }

  rbuf[wv][lane] = hin[(size_t)n * 64 + lane];
  float h2 = fcb[lane];
  const float4* rv = (const float4*)rbuf[wv];
#pragma unroll
  for (int kk = 0; kk < 16; ++kk) h2 = dot4(fw[kk], rv[kk], h2);

  if (k == 19) {  // pred head on last group
    float pv = lrelu(h2) * fcoW[lane];
    pv = wave_sum(pv);
    if (lane == 0) pred[i] = pv + fcob[0];
  }

  rbuf2[wv][lane] = h2;
  float zz = alinb[lane];
  const float4* rv2 = (const float4*)rbuf2[wv];
#pragma unroll
  for (int kk = 0; kk < 16; ++kk) zz = dot4(aw[kk], rv2[kk], zz);
  zout[((size_t)i * 20 + k) * 64 + lane] = tanh_f(zz);
}

// ---------------------------------------------------------------------------
// ALSTM head: scores = tanh(r @ att1.T + b1) @ att2.T, softmax over k (20),
// out_att = sum_k p_k r[:,k,:], alstm_out = [r_last ; out_att] @ al_out.T + b.
// One wave per sequence i.
// ---------------------------------------------------------------------------
__launch_bounds__(256)
__global__ void alstm_head(const float* __restrict__ r1,  // [512][20][64]
                           const float* __restrict__ W1,  // [32][64]
                           const float* __restrict__ b1,  // [32]
                           const float* __restrict__ W2,  // [32]
                           const float* __restrict__ Wo,  // [128]
                           const float* __restrict__ bo,  // [1]
                           float* __restrict__ alstm_out) {
  const int wv = threadIdx.x >> 6;
  const int lane = threadIdx.x & 63;
  const int i = blockIdx.x * 4 + wv;  // [0,512)
  const int e = lane & 31;
  __shared__ __align__(16) float rbuf[4][64];
  __shared__ float scb[4][20];

  float4 w1r[16];
  {
    const float4* p = (const float4*)(W1 + e * 64);
#pragma unroll
    for (int kk = 0; kk < 16; ++kk) w1r[kk] = p[kk];
  }
  const float b1e = b1[e];
  const float w2e = W2[e];

  for (int k = 0; k < 20; ++k) {
    rbuf[wv][lane] = r1[((size_t)i * 20 + k) * 64 + lane];
    float u = b1e;
    const float4* rp = (const float4*)rbuf[wv];
#pragma unroll
    for (int kk = 0; kk < 16; ++kk) u = dot4(w1r[kk], rp[kk], u);
    u = tanh_f(u) * w2e;
#pragma unroll
    for (int m = 16; m; m >>= 1) u += __shfl_xor(u, m);  // reduce within 32
    if (lane == 0) scb[wv][k] = u;
  }

  float mx = -1e30f;
#pragma unroll
  for (int k = 0; k < 20; ++k) mx = fmaxf(mx, scb[wv][k]);
  float p[20];
  float l = 0.0f;
#pragma unroll
  for (int k = 0; k < 20; ++k) {
    p[k] = __expf(scb[wv][k] - mx);
    l += p[k];
  }
  const float inv = fast_rcp(l);

  float oa = 0.0f, rlast = 0.0f;
#pragma unroll
  for (int k = 0; k < 20; ++k) {
    float rv = r1[((size_t)i * 20 + k) * 64 + lane];
    oa = fmaf(p[k], rv, oa);
    if (k == 19) rlast = rv;
  }
  oa *= inv;
  float v = fmaf(Wo[lane], rlast, Wo[64 + lane] * oa);
  v = wave_sum(v);
  if (lane == 0) alstm_out[i] = v + bo[0];
}

// ---------------------------------------------------------------------------
extern "C" void kernel_launch(void* const* d_in, const int* in_sizes, int n_in,
                              void* d_out, int out_size, void* d_ws, size_t ws_size,
                              hipStream_t stream) {
  const float* x      = (const float*)d_in[0];
  const float* Wih0   = (const float*)d_in[1];
  const float* Whh0   = (const float*)d_in[2];
  const float* bih0   = (const float*)d_in[3];
  const float* bhh0   = (const float*)d_in[4];
  const float* Wih1   = (const float*)d_in[5];
  const float* Whh1   = (const float*)d_in[6];
  const float* bih1   = (const float*)d_in[7];
  const float* bhh1   = (const float*)d_in[8];
  const float* transW = (const float*)d_in[9];
  const float* transb = (const float*)d_in[10];
  const float* a_vec  = (const float*)d_in[11];
  const float* fcW    = (const float*)d_in[12];
  const float* fcb    = (const float*)d_in[13];
  const float* fcoW   = (const float*)d_in[14];
  const float* fcob   = (const float*)d_in[15];
  const float* alinW  = (const float*)d_in[16];
  const float* alinb  = (const float*)d_in[17];
  const float* aWih0  = (const float*)d_in[18];
  const float* aWhh0  = (const float*)d_in[19];
  const float* abih0  = (const float*)d_in[20];
  const float* abhh0  = (const float*)d_in[21];
  const float* aWih1  = (const float*)d_in[22];
  const float* aWhh1  = (const float*)d_in[23];
  const float* abih1  = (const float*)d_in[24];
  const float* abhh1  = (const float*)d_in[25];
  const float* att1W  = (const float*)d_in[26];
  const float* att1b  = (const float*)d_in[27];
  const float* att2W  = (const float*)d_in[28];
  const float* aloutW = (const float*)d_in[29];
  const float* aloutb = (const float*)d_in[30];

  float* out = (float*)d_out;  // [0:512) alstm_out, [512:1024) pred

  float* W = (float*)d_ws;     // ~10.6 MB total
  float* h_enc = W; W += 10240 * 64;
  float* vbuf  = W; W += 256;
  float* s_src = W; W += 10240;
  float* s_dst = W; W += 10240;
  float* hout  = W; W += 10240 * 64;
  float* zbuf  = W; W += 512 * 20 * 64;
  float* r1    = W; W += 512 * 20 * 64;

  // 1) fused 2-layer GRU encoder over T=60, last hidden only
  gru2_fused<6, false><<<5120, 384, 0, stream>>>(
      x, 60 * 6, 6, 60, Wih0, Whh0, bih0, bhh0, Wih1, Whh1, bih1, bhh1,
      h_enc, nullptr);
  // 2) GAT score-vector prep
  gat_prep<<<1, 64, 0, stream>>>(transW, transb, a_vec, vbuf);
  // 3) per-row s_src/s_dst
  gat_svals<<<2560, 256, 0, stream>>>(h_enc, vbuf, s_src, s_dst);
  // 4) dense attention + residual
  gat_attn<<<2560, 256, 0, stream>>>(h_enc, s_src, s_dst, hout);
  // 5) fc + pred head + ALSTM input transform (z in [i][k][64])
  gat_out<<<2560, 256, 0, stream>>>(hout, fcW, fcb, fcoW, fcob, alinW, alinb,
                                    zbuf, out + 512);
  // 6) fused 2-layer ALSTM GRU over K=20, full sequence out
  gru2_fused<64, true><<<256, 384, 0, stream>>>(
      zbuf, 20 * 64, 64, 20, aWih0, aWhh0, abih0, abhh0, aWih1, aWhh1, abih1,
      abhh1, nullptr, r1);
  // 7) ALSTM attention head -> alstm_out
  alstm_head<<<128, 256, 0, stream>>>(r1, att1W, att1b, att2W, aloutW, aloutb,
                                      out);
}

// Round 2
// 39175.980 us; speedup vs baseline: 1.3512x; 1.3512x over previous
//
#include <hip/hip_runtime.h>
#include <hip/hip_bf16.h>

#define DEV __device__ __forceinline__

DEV float fast_rcp(float x) {
#if __has_builtin(__builtin_amdgcn_rcpf)
  return __builtin_amdgcn_rcpf(x);
#else
  return 1.0f / x;
#endif
}
DEV float sigm(float x) { return fast_rcp(1.0f + __expf(-x)); }
DEV float tanh_f(float x) {
  float e = __expf(-2.0f * fabsf(x));
  float t = 1.0f - 2.0f * e * fast_rcp(1.0f + e);
  return copysignf(t, x);
}
DEV float lrelu(float x) { return x > 0.0f ? x : 0.01f * x; }

DEV float wave_sum(float v) {
#pragma unroll
  for (int m = 32; m; m >>= 1) v += __shfl_xor(v, m);
  return v;
}
DEV float wave_max(float v) {
#pragma unroll
  for (int m = 32; m; m >>= 1) v = fmaxf(v, __shfl_xor(v, m));
  return v;
}
DEV float dot4(float4 w, float4 x, float acc) {
  acc = fmaf(w.x, x.x, acc);
  acc = fmaf(w.y, x.y, acc);
  acc = fmaf(w.z, x.z, acc);
  acc = fmaf(w.w, x.w, acc);
  return acc;
}

// ---------------------------------------------------------------------------
// Fused 2-layer GRU. Block = 384 threads: waves 0-2 = layer0, waves 3-5 =
// layer1 (pipelined one timestep behind; h0_t handed off via LDS double
// buffer). 2 sequences per block. Per-thread: one gate-row (g,j), weights in
// registers, h-state read as float4 wave-broadcast from LDS.
// NOTE: no min-occupancy launch bound — __launch_bounds__(384,3) made the
// allocator cap VGPRs at 84 and spill the 128-VGPR weight arrays to scratch
// (147 GB HBM traffic, 2.5% VALUBusy, 53 ms). ~155 VGPRs still fits
// 3 waves/SIMD (2 blocks/CU) naturally.
// ---------------------------------------------------------------------------
template <int I0, bool WRITE_FULL>
__launch_bounds__(384)
__global__ void gru2_fused(const float* __restrict__ xin, int sstride, int tstride, int T,
                           const float* __restrict__ Wih0, const float* __restrict__ Whh0,
                           const float* __restrict__ bih0, const float* __restrict__ bhh0,
                           const float* __restrict__ Wih1, const float* __restrict__ Whh1,
                           const float* __restrict__ bih1, const float* __restrict__ bhh1,
                           float* __restrict__ out_last, float* __restrict__ out_full) {
  constexpr int IPAD = (I0 > 8) ? 64 : 8;
  const int tid = threadIdx.x;
  const int group = tid / 192;      // 0 = layer0, 1 = layer1 (wave-uniform)
  const int lt = tid - group * 192;
  const int g = lt >> 6;            // gate: 0=r 1=z 2=n
  const int j = lt & 63;            // hidden unit
  const int row = g * 64 + j;       // gate row in [0,192)
  const int s0 = blockIdx.x * 2;    // first sequence of this block

  __shared__ __align__(16) float h0s[2][64];        // layer0 state per seq
  __shared__ __align__(16) float h1s[2][64];        // layer1 state
  __shared__ __align__(16) float h0out[2][2][64];   // [buf][seq][j] L0->L1 handoff
  __shared__ __align__(16) float xbuf[2][2][IPAD];  // staged input, double buffer
  __shared__ float gbuf[2][2][2][64];               // [group][gate r/z][seq][j]

  const float* bih = group ? bih1 : bih0;
  const float* bhh = group ? bhh1 : bhh0;
  const float bx = bih[row];
  const float bh = bhh[row];

  // recurrent weights (row of Whh) in registers
  float4 whh4[16];
  {
    const float* Whh = group ? Whh1 : Whh0;
    const float4* wp = (const float4*)(Whh + row * 64);
#pragma unroll
    for (int kk = 0; kk < 16; ++kk) whh4[kk] = wp[kk];
  }
  // input weights
  float4 wih4[16];
  float wih_s[(I0 <= 8) ? I0 : 1];
  if (group == 1) {
    const float4* wp = (const float4*)(Wih1 + row * 64);
#pragma unroll
    for (int kk = 0; kk < 16; ++kk) wih4[kk] = wp[kk];
  } else {
    if constexpr (I0 > 8) {
      const float4* wp = (const float4*)(Wih0 + row * 64);
#pragma unroll
      for (int kk = 0; kk < 16; ++kk) wih4[kk] = wp[kk];
    } else {
#pragma unroll
      for (int i = 0; i < I0; ++i) wih_s[i] = Wih0[row * I0 + i];
    }
  }

  // init states + stage x[t=0]
  if (tid < 128) { (&h0s[0][0])[tid] = 0.0f; (&h1s[0][0])[tid] = 0.0f; }
  if (tid < 2 * I0) {
    int s = tid / I0, i = tid - s * I0;
    xbuf[0][s][i] = xin[(size_t)(s0 + s) * sstride + i];
  }
  __syncthreads();

  for (int t = 0; t <= T; ++t) {
    const bool active = group ? (t >= 1) : (t < T);
    float ax0, ax1, ah0, ah1;

    // prefetch next x into registers (written to LDS in phase B)
    float xpre = 0.0f;
    int ps = 0, pi = 0;
    const bool do_pre = (tid < 2 * I0) && (t + 1 < T);
    if (do_pre) {
      ps = tid / I0; pi = tid - ps * I0;
      xpre = xin[(size_t)(s0 + ps) * sstride + (size_t)(t + 1) * tstride + pi];
    }

    if (active) {
      ax0 = bx; ax1 = bx; ah0 = bh; ah1 = bh;
      const float4* hr0 = (const float4*)(group ? h1s[0] : h0s[0]);
      const float4* hr1 = (const float4*)(group ? h1s[1] : h0s[1]);
#pragma unroll
      for (int kk = 0; kk < 16; ++kk) {
        float4 w = whh4[kk];
        ah0 = dot4(w, hr0[kk], ah0);
        ah1 = dot4(w, hr1[kk], ah1);
      }
      if (group == 1) {
        const float4* xr0 = (const float4*)(h0out[(t - 1) & 1][0]);
        const float4* xr1 = (const float4*)(h0out[(t - 1) & 1][1]);
#pragma unroll
        for (int kk = 0; kk < 16; ++kk) {
          float4 w = wih4[kk];
          ax0 = dot4(w, xr0[kk], ax0);
          ax1 = dot4(w, xr1[kk], ax1);
        }
      } else if constexpr (I0 > 8) {
        const float4* xr0 = (const float4*)(xbuf[t & 1][0]);
        const float4* xr1 = (const float4*)(xbuf[t & 1][1]);
#pragma unroll
        for (int kk = 0; kk < 16; ++kk) {
          float4 w = wih4[kk];
          ax0 = dot4(w, xr0[kk], ax0);
          ax1 = dot4(w, xr1[kk], ax1);
        }
      } else {
#pragma unroll
        for (int i = 0; i < I0; ++i) {
          float w = wih_s[i];
          ax0 = fmaf(w, xbuf[t & 1][0][i], ax0);
          ax1 = fmaf(w, xbuf[t & 1][1][i], ax1);
        }
      }
      if (g < 2) {
        gbuf[group][g][0][j] = sigm(ax0 + ah0);
        gbuf[group][g][1][j] = sigm(ax1 + ah1);
      }
    }
    __syncthreads();  // gates visible; L0's h0out[t-1] reads done before overwrite

    if (active && g == 2) {
#pragma unroll
      for (int s = 0; s < 2; ++s) {
        float axs = s ? ax1 : ax0;
        float ahs = s ? ah1 : ah0;
        float r = gbuf[group][0][s][j];
        float z = gbuf[group][1][s][j];
        float n = tanh_f(axs + r * ahs);
        float* hp = group ? h1s[s] : h0s[s];
        float hn = (1.0f - z) * n + z * hp[j];
        hp[j] = hn;
        if (group == 0) {
          h0out[t & 1][s][j] = hn;
        } else {
          const int step = t - 1;
          const int seq = s0 + s;
          if constexpr (WRITE_FULL) {
            out_full[((size_t)seq * T + step) * 64 + j] = hn;
          } else {
            if (step == T - 1) out_last[(size_t)seq * 64 + j] = hn;
          }
        }
      }
    }
    if (do_pre) xbuf[(t + 1) & 1][ps][pi] = xpre;
    __syncthreads();
  }
}

// ---------------------------------------------------------------------------
// GAT algebraic prep: v_dst[d] = sum_e trans_W[e][d]*a[e], v_src with a[64+e];
// c_dst/c_src from trans_b.  vbuf = [v_dst(64) | v_src(64) | c_dst | c_src]
// ---------------------------------------------------------------------------
__global__ void gat_prep(const float* __restrict__ tW, const float* __restrict__ tb,
                         const float* __restrict__ a, float* __restrict__ vbuf) {
  const int d = threadIdx.x;  // 64 threads
  float vd = 0.0f, vs = 0.0f;
  for (int e = 0; e < 64; ++e) {
    float w = tW[e * 64 + d];
    vd = fmaf(w, a[e], vd);
    vs = fmaf(w, a[64 + e], vs);
  }
  vbuf[d] = vd;
  vbuf[64 + d] = vs;
  if (d == 0) {
    float cd = 0.0f, cs = 0.0f;
    for (int e = 0; e < 64; ++e) {
      cd = fmaf(tb[e], a[e], cd);
      cs = fmaf(tb[e], a[64 + e], cs);
    }
    vbuf[128] = cd;
    vbuf[129] = cs;
  }
}

// s_src[n], s_dst[n] per encoder row (one wave per row)
__global__ void gat_svals(const float* __restrict__ h_enc, const float* __restrict__ vbuf,
                          float* __restrict__ s_src, float* __restrict__ s_dst) {
  const int wave = (blockIdx.x * blockDim.x + threadIdx.x) >> 6;
  const int lane = threadIdx.x & 63;
  float h = h_enc[(size_t)wave * 64 + lane];
  float pd = h * vbuf[lane];
  float ps = h * vbuf[64 + lane];
  pd = wave_sum(pd);
  ps = wave_sum(ps);
  if (lane == 0) {
    s_dst[wave] = pd + vbuf[128];
    s_src[wave] = ps + vbuf[129];
  }
}

// ---------------------------------------------------------------------------
// Dense all-pairs attention per group k (m=512): softmax_j leaky(s_i+s_j),
// weighted sum of h[k,j,:], + residual. One wave per row i; p-buffer in LDS
// (wave-private, no block barriers in the row loop); h streamed from L2.
// grid = 20 groups * 128 tiles, block = 256 (4 rows).
// ---------------------------------------------------------------------------
__launch_bounds__(256)
__global__ void gat_attn(const float* __restrict__ h_enc,
                         const float* __restrict__ s_src,
                         const float* __restrict__ s_dst,
                         float* __restrict__ hout) {
  const int k = blockIdx.x >> 7;
  const int tile = blockIdx.x & 127;
  const int wv = threadIdx.x >> 6;
  const int lane = threadIdx.x & 63;
  const int i = tile * 4 + wv;
  __shared__ float sdbuf[512];
  __shared__ __align__(16) float pbuf[4][512];

  for (int u = threadIdx.x; u < 512; u += 256) sdbuf[u] = s_dst[k * 512 + u];
  __syncthreads();

  const float si = s_src[k * 512 + i];
  float ev[8];
  float mx = -1e30f;
#pragma unroll
  for (int u = 0; u < 8; ++u) {
    ev[u] = lrelu(si + sdbuf[lane + u * 64]);
    mx = fmaxf(mx, ev[u]);
  }
  mx = wave_max(mx);
  float lsum = 0.0f;
#pragma unroll
  for (int u = 0; u < 8; ++u) {
    float p = __expf(ev[u] - mx);
    pbuf[wv][lane + u * 64] = p;
    lsum += p;
  }
  lsum = wave_sum(lsum);
  const float inv = fast_rcp(lsum);

  const float* hk = h_enc + (size_t)k * 512 * 64;
  const float4* pv = (const float4*)pbuf[wv];
  float acc0 = 0.0f, acc1 = 0.0f;
#pragma unroll 2
  for (int jj = 0; jj < 128; ++jj) {
    float4 p = pv[jj];
    const float* hp = hk + (size_t)(jj * 4) * 64 + lane;
    acc0 = fmaf(p.x, hp[0], acc0);
    acc1 = fmaf(p.y, hp[64], acc1);
    acc0 = fmaf(p.z, hp[128], acc0);
    acc1 = fmaf(p.w, hp[192], acc1);
  }
  hout[((size_t)k * 512 + i) * 64 + lane] =
      (acc0 + acc1) * inv + hk[(size_t)i * 64 + lane];
}

// ---------------------------------------------------------------------------
// Post-GAT transform: h2 = fc(hout); pred head (k==19); z = tanh(al_in(h2))
// written in [i][k][64] layout for the ALSTM scan. One wave per row.
// ---------------------------------------------------------------------------
__launch_bounds__(256)
__global__ void gat_out(const float* __restrict__ hin,
                        const float* __restrict__ fcW, const float* __restrict__ fcb,
                        const float* __restrict__ fcoW, const float* __restrict__ fcob,
                        const float* __restrict__ alinW, const float* __restrict__ alinb,
                        float* __restrict__ zout, float* __restrict__ pred) {
  const int wv = threadIdx.x >> 6;
  const int lane = threadIdx.x & 63;
  const int n = blockIdx.x * 4 + wv;  // [0,10240)
  const int k = n >> 9;
  const int i = n & 511;
  __shared__ __align__(16) float rbuf[4][64];
  __shared__ __align__(16) float rbuf2[4][64];

  float4 fw[16], aw[16];
  {
    const float4* p1 = (const float4*)(fcW + lane * 64);
    const float4* p2 = (const float4*)(alinW + lane * 64);
#pragma unroll
    for (int kk = 0; kk < 16; ++kk) fw[kk] = p1[kk];
#pragma unroll
    for (int kk = 0; kk < 16; ++kk) aw[kk] = p2[kk];
  }

  rbuf[wv][lane] = hin[(size_t)n * 64 + lane];
  float h2 = fcb[lane];
  const float4* rv = (const float4*)rbuf[wv];
#pragma unroll
  for (int kk = 0; kk < 16; ++kk) h2 = dot4(fw[kk], rv[kk], h2);

  if (k == 19) {  // pred head on last group
    float pv = lrelu(h2) * fcoW[lane];
    pv = wave_sum(pv);
    if (lane == 0) pred[i] = pv + fcob[0];
  }

  rbuf2[wv][lane] = h2;
  float zz = alinb[lane];
  const float4* rv2 = (const float4*)rbuf2[wv];
#pragma unroll
  for (int kk = 0; kk < 16; ++kk) zz = dot4(aw[kk], rv2[kk], zz);
  zout[((size_t)i * 20 + k) * 64 + lane] = tanh_f(zz);
}

// ---------------------------------------------------------------------------
// ALSTM head: scores = tanh(r @ att1.T + b1) @ att2.T, softmax over k (20),
// out_att = sum_k p_k r[:,k,:], alstm_out = [r_last ; out_att] @ al_out.T + b.
// One wave per sequence i.
// ---------------------------------------------------------------------------
__launch_bounds__(256)
__global__ void alstm_head(const float* __restrict__ r1,  // [512][20][64]
                           const float* __restrict__ W1,  // [32][64]
                           const float* __restrict__ b1,  // [32]
                           const float* __restrict__ W2,  // [32]
                           const float* __restrict__ Wo,  // [128]
                           const float* __restrict__ bo,  // [1]
                           float* __restrict__ alstm_out) {
  const int wv = threadIdx.x >> 6;
  const int lane = threadIdx.x & 63;
  const int i = blockIdx.x * 4 + wv;  // [0,512)
  const int e = lane & 31;
  __shared__ __align__(16) float rbuf[4][64];
  __shared__ float scb[4][20];

  float4 w1r[16];
  {
    const float4* p = (const float4*)(W1 + e * 64);
#pragma unroll
    for (int kk = 0; kk < 16; ++kk) w1r[kk] = p[kk];
  }
  const float b1e = b1[e];
  const float w2e = W2[e];

  for (int k = 0; k < 20; ++k) {
    rbuf[wv][lane] = r1[((size_t)i * 20 + k) * 64 + lane];
    float u = b1e;
    const float4* rp = (const float4*)rbuf[wv];
#pragma unroll
    for (int kk = 0; kk < 16; ++kk) u = dot4(w1r[kk], rp[kk], u);
    u = tanh_f(u) * w2e;
#pragma unroll
    for (int m = 16; m; m >>= 1) u += __shfl_xor(u, m);  // reduce within 32
    if (lane == 0) scb[wv][k] = u;
  }

  float mx = -1e30f;
#pragma unroll
  for (int k = 0; k < 20; ++k) mx = fmaxf(mx, scb[wv][k]);
  float p[20];
  float l = 0.0f;
#pragma unroll
  for (int k = 0; k < 20; ++k) {
    p[k] = __expf(scb[wv][k] - mx);
    l += p[k];
  }
  const float inv = fast_rcp(l);

  float oa = 0.0f, rlast = 0.0f;
#pragma unroll
  for (int k = 0; k < 20; ++k) {
    float rv = r1[((size_t)i * 20 + k) * 64 + lane];
    oa = fmaf(p[k], rv, oa);
    if (k == 19) rlast = rv;
  }
  oa *= inv;
  float v = fmaf(Wo[lane], rlast, Wo[64 + lane] * oa);
  v = wave_sum(v);
  if (lane == 0) alstm_out[i] = v + bo[0];
}

// ---------------------------------------------------------------------------
extern "C" void kernel_launch(void* const* d_in, const int* in_sizes, int n_in,
                              void* d_out, int out_size, void* d_ws, size_t ws_size,
                              hipStream_t stream) {
  const float* x      = (const float*)d_in[0];
  const float* Wih0   = (const float*)d_in[1];
  const float* Whh0   = (const float*)d_in[2];
  const float* bih0   = (const float*)d_in[3];
  const float* bhh0   = (const float*)d_in[4];
  const float* Wih1   = (const float*)d_in[5];
  const float* Whh1   = (const float*)d_in[6];
  const float* bih1   = (const float*)d_in[7];
  const float* bhh1   = (const float*)d_in[8];
  const float* transW = (const float*)d_in[9];
  const float* transb = (const float*)d_in[10];
  const float* a_vec  = (const float*)d_in[11];
  const float* fcW    = (const float*)d_in[12];
  const float* fcb    = (const float*)d_in[13];
  const float* fcoW   = (const float*)d_in[14];
  const float* fcob   = (const float*)d_in[15];
  const float* alinW  = (const float*)d_in[16];
  const float* alinb  = (const float*)d_in[17];
  const float* aWih0  = (const float*)d_in[18];
  const float* aWhh0  = (const float*)d_in[19];
  const float* abih0  = (const float*)d_in[20];
  const float* abhh0  = (const float*)d_in[21];
  const float* aWih1  = (const float*)d_in[22];
  const float* aWhh1  = (const float*)d_in[23];
  const float* abih1  = (const float*)d_in[24];
  const float* abhh1  = (const float*)d_in[25];
  const float* att1W  = (const float*)d_in[26];
  const float* att1b  = (const float*)d_in[27];
  const float* att2W  = (const float*)d_in[28];
  const float* aloutW = (const float*)d_in[29];
  const float* aloutb = (const float*)d_in[30];

  float* out = (float*)d_out;  // [0:512) alstm_out, [512:1024) pred

  float* W = (float*)d_ws;     // ~10.6 MB total
  float* h_enc = W; W += 10240 * 64;
  float* vbuf  = W; W += 256;
  float* s_src = W; W += 10240;
  float* s_dst = W; W += 10240;
  float* hout  = W; W += 10240 * 64;
  float* zbuf  = W; W += 512 * 20 * 64;
  float* r1    = W; W += 512 * 20 * 64;

  // 1) fused 2-layer GRU encoder over T=60, last hidden only
  gru2_fused<6, false><<<5120, 384, 0, stream>>>(
      x, 60 * 6, 6, 60, Wih0, Whh0, bih0, bhh0, Wih1, Whh1, bih1, bhh1,
      h_enc, nullptr);
  // 2) GAT score-vector prep
  gat_prep<<<1, 64, 0, stream>>>(transW, transb, a_vec, vbuf);
  // 3) per-row s_src/s_dst
  gat_svals<<<2560, 256, 0, stream>>>(h_enc, vbuf, s_src, s_dst);
  // 4) dense attention + residual
  gat_attn<<<2560, 256, 0, stream>>>(h_enc, s_src, s_dst, hout);
  // 5) fc + pred head + ALSTM input transform (z in [i][k][64])
  gat_out<<<2560, 256, 0, stream>>>(hout, fcW, fcb, fcoW, fcob, alinW, alinb,
                                    zbuf, out + 512);
  // 6) fused 2-layer ALSTM GRU over K=20, full sequence out
  gru2_fused<64, true><<<256, 384, 0, stream>>>(
      zbuf, 20 * 64, 64, 20, aWih0, aWhh0, abih0, abhh0, aWih1, aWhh1, abih1,
      abhh1, nullptr, r1);
  // 7) ALSTM attention head -> alstm_out
  alstm_head<<<128, 256, 0, stream>>>(r1, att1W, att1b, att2W, aloutW, aloutb,
                                      out);
}

// Round 4
// 11075.899 us; speedup vs baseline: 4.7791x; 3.5370x over previous
//
#include <hip/hip_runtime.h>
#include <hip/hip_bf16.h>

#define DEV __device__ __forceinline__

DEV float fast_rcp(float x) {
#if __has_builtin(__builtin_amdgcn_rcpf)
  return __builtin_amdgcn_rcpf(x);
#else
  return 1.0f / x;
#endif
}
DEV float sigm(float x) { return fast_rcp(1.0f + __expf(-x)); }
DEV float tanh_f(float x) {
  float e = __expf(-2.0f * fabsf(x));
  float t = 1.0f - 2.0f * e * fast_rcp(1.0f + e);
  return copysignf(t, x);
}
DEV float lrelu(float x) { return x > 0.0f ? x : 0.01f * x; }

DEV float wave_sum(float v) {
#pragma unroll
  for (int m = 32; m; m >>= 1) v += __shfl_xor(v, m);
  return v;
}
DEV float wave_max(float v) {
#pragma unroll
  for (int m = 32; m; m >>= 1) v = fmaxf(v, __shfl_xor(v, m));
  return v;
}
DEV float dot4(float4 w, float4 x, float acc) {
  acc = fmaf(w.x, x.x, acc);
  acc = fmaf(w.y, x.y, acc);
  acc = fmaf(w.z, x.z, acc);
  acc = fmaf(w.w, x.w, acc);
  return acc;
}

// ---------------------------------------------------------------------------
// Fused 2-layer GRU, split-K lane pairing.
// Block = 768 threads: [group(2 layers)][row(192)][half(2)].
//   group 0 = layer0, group 1 = layer1 (pipelined one step behind, LDS handoff)
//   half   = K-half of the dot product; even/odd lanes pair via __shfl_xor(.,1)
// 2 sequences per block. Per-thread weights: half a Whh row (8 float4) + half
// a Wih row (8 float4 or 3 scalars) = ~64 VGPRs -> no spill (R1: 128-VGPR
// weight arrays forced spill-to-scratch, 85-147 GB HBM, 2.5-3.5% VALUBusy).
// R3 BUG FIX: IH (x-side float4s per half) was (I0/8)/2 = half the correct
// count — ALSTM layer-0 x-dot covered only 32/64 inputs. Correct: I0/8.
// PyTorch gate order r,z,n: r=sig(xr+hr) z=sig(xz+hz) n=tanh(xn+r*hn),
// h=(1-z)n+z*h  (bih folded into ax on half 0, bhh into ah on half 0).
// ---------------------------------------------------------------------------
template <int I0, bool WRITE_FULL>
__launch_bounds__(768)
__global__ void gru2_fused(const float* __restrict__ xin, int sstride, int tstride, int T,
                           const float* __restrict__ Wih0, const float* __restrict__ Whh0,
                           const float* __restrict__ bih0, const float* __restrict__ bhh0,
                           const float* __restrict__ Wih1, const float* __restrict__ Whh1,
                           const float* __restrict__ bih1, const float* __restrict__ bhh1,
                           float* __restrict__ out_last, float* __restrict__ out_full) {
  constexpr int IPAD = (I0 > 8) ? 64 : 8;
  constexpr int IH = (I0 > 8) ? I0 / 8 : 0;         // float4s per half (x-side)
  constexpr int ISH = (I0 <= 8) ? I0 / 2 : 1;       // scalars per half (x-side)
  const int tid = threadIdx.x;
  const int group = tid / 384;       // 0 = layer0, 1 = layer1 (wave-uniform)
  const int lt = tid - group * 384;
  const int row = lt >> 1;           // gate row in [0,192)
  const int half = lt & 1;           // K-half
  const int g = row >> 6;            // gate: 0=r 1=z 2=n
  const int j = row & 63;            // hidden unit
  const int s0 = blockIdx.x * 2;     // first sequence of this block

  __shared__ __align__(16) float h0s[2][64];        // layer0 state per seq
  __shared__ __align__(16) float h1s[2][64];        // layer1 state
  __shared__ __align__(16) float h0out[2][2][64];   // [buf][seq][j] L0->L1 handoff
  __shared__ __align__(16) float xbuf[2][2][IPAD];  // staged input, double buffer
  __shared__ float gbuf[2][2][2][64];               // [group][gate r/z][seq][j]

  // biases only on half 0 (halves are summed via shfl)
  const float bx = half ? 0.0f : (group ? bih1[row] : bih0[row]);
  const float bh = half ? 0.0f : (group ? bhh1[row] : bhh0[row]);

  // recurrent weights: half a row of Whh (32 floats = 8 float4)
  float4 whh4[8];
  {
    const float* Whh = group ? Whh1 : Whh0;
    const float4* wp = (const float4*)(Whh + row * 64 + half * 32);
#pragma unroll
    for (int kk = 0; kk < 8; ++kk) whh4[kk] = wp[kk];
  }
  // input weights: half a row of Wih
  float4 wih4[8];
  float wih_s[(I0 <= 8) ? ISH : 1];
  if (group == 1) {
    const float4* wp = (const float4*)(Wih1 + row * 64 + half * 32);
#pragma unroll
    for (int kk = 0; kk < 8; ++kk) wih4[kk] = wp[kk];
  } else {
    if constexpr (I0 > 8) {
      const float4* wp = (const float4*)(Wih0 + row * I0 + half * (I0 / 2));
#pragma unroll
      for (int kk = 0; kk < IH; ++kk) wih4[kk] = wp[kk];
    } else {
#pragma unroll
      for (int i = 0; i < ISH; ++i) wih_s[i] = Wih0[row * I0 + half * ISH + i];
    }
  }

  // init states + stage x[t=0]
  if (tid < 128) { (&h0s[0][0])[tid] = 0.0f; (&h1s[0][0])[tid] = 0.0f; }
  if (tid < 2 * I0) {
    int s = tid / I0, i = tid - s * I0;
    xbuf[0][s][i] = xin[(size_t)(s0 + s) * sstride + i];
  }
  __syncthreads();

  for (int t = 0; t <= T; ++t) {
    const bool active = group ? (t >= 1) : (t < T);
    float ax0, ax1, ah0, ah1;

    // prefetch next x into registers (written to LDS in phase B)
    float xpre = 0.0f;
    int ps = 0, pi = 0;
    const bool do_pre = (tid < 2 * I0) && (t + 1 < T);
    if (do_pre) {
      ps = tid / I0; pi = tid - ps * I0;
      xpre = xin[(size_t)(s0 + ps) * sstride + (size_t)(t + 1) * tstride + pi];
    }

    if (active) {
      ax0 = bx; ax1 = bx; ah0 = bh; ah1 = bh;
      const float4* hr0 = (const float4*)((group ? h1s[0] : h0s[0]) + half * 32);
      const float4* hr1 = (const float4*)((group ? h1s[1] : h0s[1]) + half * 32);
#pragma unroll
      for (int kk = 0; kk < 8; ++kk) {
        float4 w = whh4[kk];
        ah0 = dot4(w, hr0[kk], ah0);
        ah1 = dot4(w, hr1[kk], ah1);
      }
      if (group == 1) {
        const float4* xr0 = (const float4*)(h0out[(t - 1) & 1][0] + half * 32);
        const float4* xr1 = (const float4*)(h0out[(t - 1) & 1][1] + half * 32);
#pragma unroll
        for (int kk = 0; kk < 8; ++kk) {
          float4 w = wih4[kk];
          ax0 = dot4(w, xr0[kk], ax0);
          ax1 = dot4(w, xr1[kk], ax1);
        }
      } else if constexpr (I0 > 8) {
        const float4* xr0 = (const float4*)(xbuf[t & 1][0] + half * (I0 / 2));
        const float4* xr1 = (const float4*)(xbuf[t & 1][1] + half * (I0 / 2));
#pragma unroll
        for (int kk = 0; kk < IH; ++kk) {
          float4 w = wih4[kk];
          ax0 = dot4(w, xr0[kk], ax0);
          ax1 = dot4(w, xr1[kk], ax1);
        }
      } else {
#pragma unroll
        for (int i = 0; i < ISH; ++i) {
          float w = wih_s[i];
          ax0 = fmaf(w, xbuf[t & 1][0][half * ISH + i], ax0);
          ax1 = fmaf(w, xbuf[t & 1][1][half * ISH + i], ax1);
        }
      }
      // combine K-halves across the even/odd lane pair (both lanes get full sum)
      ax0 += __shfl_xor(ax0, 1);
      ax1 += __shfl_xor(ax1, 1);
      ah0 += __shfl_xor(ah0, 1);
      ah1 += __shfl_xor(ah1, 1);
      if (g < 2 && half == 0) {
        gbuf[group][g][0][j] = sigm(ax0 + ah0);
        gbuf[group][g][1][j] = sigm(ax1 + ah1);
      }
    }
    __syncthreads();  // gates visible; L0's h0out[t-1] reads done before overwrite

    if (active && g == 2 && half == 0) {
#pragma unroll
      for (int s = 0; s < 2; ++s) {
        float axs = s ? ax1 : ax0;
        float ahs = s ? ah1 : ah0;
        float r = gbuf[group][0][s][j];
        float z = gbuf[group][1][s][j];
        float n = tanh_f(axs + r * ahs);
        float* hp = group ? h1s[s] : h0s[s];
        float hn = (1.0f - z) * n + z * hp[j];
        hp[j] = hn;
        if (group == 0) {
          h0out[t & 1][s][j] = hn;
        } else {
          const int step = t - 1;
          const int seq = s0 + s;
          if constexpr (WRITE_FULL) {
            out_full[((size_t)seq * T + step) * 64 + j] = hn;
          } else {
            if (step == T - 1) out_last[(size_t)seq * 64 + j] = hn;
          }
        }
      }
    }
    if (do_pre) xbuf[(t + 1) & 1][ps][pi] = xpre;
    __syncthreads();
  }
}

// ---------------------------------------------------------------------------
// GAT algebraic prep: v_dst[d] = sum_e trans_W[e][d]*a[e], v_src with a[64+e];
// c_dst/c_src from trans_b.  vbuf = [v_dst(64) | v_src(64) | c_dst | c_src]
// ---------------------------------------------------------------------------
__global__ void gat_prep(const float* __restrict__ tW, const float* __restrict__ tb,
                         const float* __restrict__ a, float* __restrict__ vbuf) {
  const int d = threadIdx.x;  // 64 threads
  float vd = 0.0f, vs = 0.0f;
  for (int e = 0; e < 64; ++e) {
    float w = tW[e * 64 + d];
    vd = fmaf(w, a[e], vd);
    vs = fmaf(w, a[64 + e], vs);
  }
  vbuf[d] = vd;
  vbuf[64 + d] = vs;
  if (d == 0) {
    float cd = 0.0f, cs = 0.0f;
    for (int e = 0; e < 64; ++e) {
      cd = fmaf(tb[e], a[e], cd);
      cs = fmaf(tb[e], a[64 + e], cs);
    }
    vbuf[128] = cd;
    vbuf[129] = cs;
  }
}

// s_src[n], s_dst[n] per encoder row (one wave per row)
__global__ void gat_svals(const float* __restrict__ h_enc, const float* __restrict__ vbuf,
                          float* __restrict__ s_src, float* __restrict__ s_dst) {
  const int wave = (blockIdx.x * blockDim.x + threadIdx.x) >> 6;
  const int lane = threadIdx.x & 63;
  float h = h_enc[(size_t)wave * 64 + lane];
  float pd = h * vbuf[lane];
  float ps = h * vbuf[64 + lane];
  pd = wave_sum(pd);
  ps = wave_sum(ps);
  if (lane == 0) {
    s_dst[wave] = pd + vbuf[128];
    s_src[wave] = ps + vbuf[129];
  }
}

// ---------------------------------------------------------------------------
// Dense all-pairs attention per group k (m=512): softmax_j leaky(s_i+s_j),
// weighted sum of h[k,j,:], + residual. One wave per row i; p-buffer in LDS
// (wave-private, no block barriers in the row loop); h streamed from L2.
// grid = 20 groups * 128 tiles, block = 256 (4 rows).
// ---------------------------------------------------------------------------
__launch_bounds__(256)
__global__ void gat_attn(const float* __restrict__ h_enc,
                         const float* __restrict__ s_src,
                         const float* __restrict__ s_dst,
                         float* __restrict__ hout) {
  const int k = blockIdx.x >> 7;
  const int tile = blockIdx.x & 127;
  const int wv = threadIdx.x >> 6;
  const int lane = threadIdx.x & 63;
  const int i = tile * 4 + wv;
  __shared__ float sdbuf[512];
  __shared__ __align__(16) float pbuf[4][512];

  for (int u = threadIdx.x; u < 512; u += 256) sdbuf[u] = s_dst[k * 512 + u];
  __syncthreads();

  const float si = s_src[k * 512 + i];
  float ev[8];
  float mx = -1e30f;
#pragma unroll
  for (int u = 0; u < 8; ++u) {
    ev[u] = lrelu(si + sdbuf[lane + u * 64]);
    mx = fmaxf(mx, ev[u]);
  }
  mx = wave_max(mx);
  float lsum = 0.0f;
#pragma unroll
  for (int u = 0; u < 8; ++u) {
    float p = __expf(ev[u] - mx);
    pbuf[wv][lane + u * 64] = p;
    lsum += p;
  }
  lsum = wave_sum(lsum);
  const float inv = fast_rcp(lsum);

  const float* hk = h_enc + (size_t)k * 512 * 64;
  const float4* pv = (const float4*)pbuf[wv];
  float acc0 = 0.0f, acc1 = 0.0f;
#pragma unroll 2
  for (int jj = 0; jj < 128; ++jj) {
    float4 p = pv[jj];
    const float* hp = hk + (size_t)(jj * 4) * 64 + lane;
    acc0 = fmaf(p.x, hp[0], acc0);
    acc1 = fmaf(p.y, hp[64], acc1);
    acc0 = fmaf(p.z, hp[128], acc0);
    acc1 = fmaf(p.w, hp[192], acc1);
  }
  hout[((size_t)k * 512 + i) * 64 + lane] =
      (acc0 + acc1) * inv + hk[(size_t)i * 64 + lane];
}

// ---------------------------------------------------------------------------
// Post-GAT transform: h2 = fc(hout); pred head (k==19); z = tanh(al_in(h2))
// written in [i][k][64] layout for the ALSTM scan. One wave per row.
// ---------------------------------------------------------------------------
__launch_bounds__(256)
__global__ void gat_out(const float* __restrict__ hin,
                        const float* __restrict__ fcW, const float* __restrict__ fcb,
                        const float* __restrict__ fcoW, const float* __restrict__ fcob,
                        const float* __restrict__ alinW, const float* __restrict__ alinb,
                        float* __restrict__ zout, float* __restrict__ pred) {
  const int wv = threadIdx.x >> 6;
  const int lane = threadIdx.x & 63;
  const int n = blockIdx.x * 4 + wv;  // [0,10240)
  const int k = n >> 9;
  const int i = n & 511;
  __shared__ __align__(16) float rbuf[4][64];
  __shared__ __align__(16) float rbuf2[4][64];

  float4 fw[16], aw[16];
  {
    const float4* p1 = (const float4*)(fcW + lane * 64);
    const float4* p2 = (const float4*)(alinW + lane * 64);
#pragma unroll
    for (int kk = 0; kk < 16; ++kk) fw[kk] = p1[kk];
#pragma unroll
    for (int kk = 0; kk < 16; ++kk) aw[kk] = p2[kk];
  }

  rbuf[wv][lane] = hin[(size_t)n * 64 + lane];
  float h2 = fcb[lane];
  const float4* rv = (const float4*)rbuf[wv];
#pragma unroll
  for (int kk = 0; kk < 16; ++kk) h2 = dot4(fw[kk], rv[kk], h2);

  if (k == 19) {  // pred head on last group
    float pv = lrelu(h2) * fcoW[lane];
    pv = wave_sum(pv);
    if (lane == 0) pred[i] = pv + fcob[0];
  }

  rbuf2[wv][lane] = h2;
  float zz = alinb[lane];
  const float4* rv2 = (const float4*)rbuf2[wv];
#pragma unroll
  for (int kk = 0; kk < 16; ++kk) zz = dot4(aw[kk], rv2[kk], zz);
  zout[((size_t)i * 20 + k) * 64 + lane] = tanh_f(zz);
}

// ---------------------------------------------------------------------------
// ALSTM head: scores = tanh(r @ att1.T + b1) @ att2.T, softmax over k (20),
// out_att = sum_k p_k r[:,k,:], alstm_out = [r_last ; out_att] @ al_out.T + b.
// One wave per sequence i.
// ---------------------------------------------------------------------------
__launch_bounds__(256)
__global__ void alstm_head(const float* __restrict__ r1,  // [512][20][64]
                           const float* __restrict__ W1,  // [32][64]
                           const float* __restrict__ b1,  // [32]
                           const float* __restrict__ W2,  // [32]
                           const float* __restrict__ Wo,  // [128]
                           const float* __restrict__ bo,  // [1]
                           float* __restrict__ alstm_out) {
  const int wv = threadIdx.x >> 6;
  const int lane = threadIdx.x & 63;
  const int i = blockIdx.x * 4 + wv;  // [0,512)
  const int e = lane & 31;
  __shared__ __align__(16) float rbuf[4][64];
  __shared__ float scb[4][20];

  float4 w1r[16];
  {
    const float4* p = (const float4*)(W1 + e * 64);
#pragma unroll
    for (int kk = 0; kk < 16; ++kk) w1r[kk] = p[kk];
  }
  const float b1e = b1[e];
  const float w2e = W2[e];

  for (int k = 0; k < 20; ++k) {
    rbuf[wv][lane] = r1[((size_t)i * 20 + k) * 64 + lane];
    float u = b1e;
    const float4* rp = (const float4*)rbuf[wv];
#pragma unroll
    for (int kk = 0; kk < 16; ++kk) u = dot4(w1r[kk], rp[kk], u);
    u = tanh_f(u) * w2e;
#pragma unroll
    for (int m = 16; m; m >>= 1) u += __shfl_xor(u, m);  // reduce within 32
    if (lane == 0) scb[wv][k] = u;
  }

  float mx = -1e30f;
#pragma unroll
  for (int k = 0; k < 20; ++k) mx = fmaxf(mx, scb[wv][k]);
  float p[20];
  float l = 0.0f;
#pragma unroll
  for (int k = 0; k < 20; ++k) {
    p[k] = __expf(scb[wv][k] - mx);
    l += p[k];
  }
  const float inv = fast_rcp(l);

  float oa = 0.0f, rlast = 0.0f;
#pragma unroll
  for (int k = 0; k < 20; ++k) {
    float rv = r1[((size_t)i * 20 + k) * 64 + lane];
    oa = fmaf(p[k], rv, oa);
    if (k == 19) rlast = rv;
  }
  oa *= inv;
  float v = fmaf(Wo[lane], rlast, Wo[64 + lane] * oa);
  v = wave_sum(v);
  if (lane == 0) alstm_out[i] = v + bo[0];
}

// ---------------------------------------------------------------------------
extern "C" void kernel_launch(void* const* d_in, const int* in_sizes, int n_in,
                              void* d_out, int out_size, void* d_ws, size_t ws_size,
                              hipStream_t stream) {
  const float* x      = (const float*)d_in[0];
  const float* Wih0   = (const float*)d_in[1];
  const float* Whh0   = (const float*)d_in[2];
  const float* bih0   = (const float*)d_in[3];
  const float* bhh0   = (const float*)d_in[4];
  const float* Wih1   = (const float*)d_in[5];
  const float* Whh1   = (const float*)d_in[6];
  const float* bih1   = (const float*)d_in[7];
  const float* bhh1   = (const float*)d_in[8];
  const float* transW = (const float*)d_in[9];
  const float* transb = (const float*)d_in[10];
  const float* a_vec  = (const float*)d_in[11];
  const float* fcW    = (const float*)d_in[12];
  const float* fcb    = (const float*)d_in[13];
  const float* fcoW   = (const float*)d_in[14];
  const float* fcob   = (const float*)d_in[15];
  const float* alinW  = (const float*)d_in[16];
  const float* alinb  = (const float*)d_in[17];
  const float* aWih0  = (const float*)d_in[18];
  const float* aWhh0  = (const float*)d_in[19];
  const float* abih0  = (const float*)d_in[20];
  const float* abhh0  = (const float*)d_in[21];
  const float* aWih1  = (const float*)d_in[22];
  const float* aWhh1  = (const float*)d_in[23];
  const float* abih1  = (const float*)d_in[24];
  const float* abhh1  = (const float*)d_in[25];
  const float* att1W  = (const float*)d_in[26];
  const float* att1b  = (const float*)d_in[27];
  const float* att2W  = (const float*)d_in[28];
  const float* aloutW = (const float*)d_in[29];
  const float* aloutb = (const float*)d_in[30];

  float* out = (float*)d_out;  // [0:512) alstm_out, [512:1024) pred

  float* W = (float*)d_ws;     // ~10.6 MB total
  float* h_enc = W; W += 10240 * 64;
  float* vbuf  = W; W += 256;
  float* s_src = W; W += 10240;
  float* s_dst = W; W += 10240;
  float* hout  = W; W += 10240 * 64;
  float* zbuf  = W; W += 512 * 20 * 64;
  float* r1    = W; W += 512 * 20 * 64;

  // 1) fused 2-layer GRU encoder over T=60, last hidden only
  gru2_fused<6, false><<<5120, 768, 0, stream>>>(
      x, 60 * 6, 6, 60, Wih0, Whh0, bih0, bhh0, Wih1, Whh1, bih1, bhh1,
      h_enc, nullptr);
  // 2) GAT score-vector prep
  gat_prep<<<1, 64, 0, stream>>>(transW, transb, a_vec, vbuf);
  // 3) per-row s_src/s_dst
  gat_svals<<<2560, 256, 0, stream>>>(h_enc, vbuf, s_src, s_dst);
  // 4) dense attention + residual
  gat_attn<<<2560, 256, 0, stream>>>(h_enc, s_src, s_dst, hout);
  // 5) fc + pred head + ALSTM input transform (z in [i][k][64])
  gat_out<<<2560, 256, 0, stream>>>(hout, fcW, fcb, fcoW, fcob, alinW, alinb,
                                    zbuf, out + 512);
  // 6) fused 2-layer ALSTM GRU over K=20, full sequence out
  gru2_fused<64, true><<<256, 768, 0, stream>>>(
      zbuf, 20 * 64, 64, 20, aWih0, aWhh0, abih0, abhh0, aWih1, aWhh1, abih1,
      abhh1, nullptr, r1);
  // 7) ALSTM attention head -> alstm_out
  alstm_head<<<128, 256, 0, stream>>>(r1, att1W, att1b, att2W, aloutW, aloutb,
                                      out);
}